// Round 16
// baseline (461.918 us; speedup 1.0000x reference)
//
#include <hip/hip_runtime.h>

#define NCLS 26
#define HID 128
#define EPB 8192   // edges per bucketing block
#define MAXBK 512  // max buckets (supports n <= 131072)
#define BCAP 6016  // fixed bucket capacity (mean 4092 + ~30 sigma for uniform input)
typedef unsigned short ushort_t;
typedef unsigned int uint_t;
typedef unsigned long long u64;

typedef __bf16 bf16x8 __attribute__((ext_vector_type(8)));
typedef float f32x4 __attribute__((ext_vector_type(4)));
typedef unsigned int u32x4 __attribute__((ext_vector_type(4)));
typedef unsigned int u32x2 __attribute__((ext_vector_type(2)));

// ---------------- bf16 helpers (ushort storage) ----------------
static __device__ __forceinline__ float b2f(ushort_t h) {
  return __uint_as_float(((uint_t)h) << 16);
}
static __device__ __forceinline__ ushort_t f2b(float f) {
  uint_t u = __float_as_uint(f);
  uint_t r = (u + 0x7fffu + ((u >> 16) & 1u)) >> 16;
  return (ushort_t)r;
}
static __device__ __forceinline__ uint_t pack2(float f0, float f1) {
  return (uint_t)f2b(f0) | ((uint_t)f2b(f1) << 16);
}
static __device__ __forceinline__ float lo16(uint_t v) { return b2f((ushort_t)(v & 0xffffu)); }
static __device__ __forceinline__ float hi16(uint_t v) { return b2f((ushort_t)(v >> 16)); }
static __device__ __forceinline__ bf16x8 ld_frag(const ushort_t* p) {
  u32x4 v = *reinterpret_cast<const u32x4*>(p);
  return __builtin_bit_cast(bf16x8, v);
}

// ---------------- preprocessing: two-level bucket sort, PADDED CSR ----------------
// bucket(c) = c >> 8 (256 nodes per bucket). Packed bucket record (u64):
// hi32 = r | (c_local << 24), lo32 = fp32 weight bits.
// Buckets live at fixed offsets b*BCAP in bkt; gcur[b] = fill count.
// Each node's meta list is padded to a multiple of 8 with {row 0, weight 0}
// entries so the SpMM inner loops need NO per-edge bounds logic.

__global__ __launch_bounds__(256) void bucket_place(
    const int* __restrict__ ei, const float* __restrict__ ew,
    int* __restrict__ gcur, u64* __restrict__ bkt, int E, int nbk) {
  __shared__ uint_t lc[MAXBK];
  __shared__ uint_t lb[MAXBK];
  int tid = threadIdx.x;
  for (int t = tid; t < nbk; t += 256) lc[t] = 0;
  __syncthreads();
  int e0 = blockIdx.x * EPB;
#pragma unroll
  for (int i = 0; i < EPB / 256; ++i) {
    int e = e0 + tid + i * 256;
    if (e < E) atomicAdd(&lc[(uint_t)ei[E + e] >> 8], 1u);
  }
  __syncthreads();
  for (int t = tid; t < nbk; t += 256) {
    uint_t c = lc[t];
    lb[t] = c ? (uint_t)t * BCAP + (uint_t)atomicAdd(&gcur[t], (int)c) : 0u;
    lc[t] = 0;
  }
  __syncthreads();
#pragma unroll
  for (int i = 0; i < EPB / 256; ++i) {
    int e = e0 + tid + i * 256;
    if (e < E) {
      uint_t r = (uint_t)ei[e];
      uint_t c = (uint_t)ei[E + e];
      uint_t b = c >> 8;
      uint_t pos = lb[b] + atomicAdd(&lc[b], 1u);
      bkt[pos] = ((u64)(r | ((c & 255u) << 24)) << 32) | (u64)__float_as_uint(ew[e]);
    }
  }
}

// per-bucket: LDS count + weighted degree; scan of PADDED counts -> local starts
// (written to start[]), bucket padded totals -> pbs[]; dinv[].
__global__ __launch_bounds__(256) void bucket_stats(
    const u64* __restrict__ bkt, const int* __restrict__ gcur,
    int* __restrict__ start, int* __restrict__ pbs, float* __restrict__ dinv, int n) {
  int b = blockIdx.x;
  __shared__ uint_t cnt[256];
  __shared__ float deg[256];
  __shared__ int ssc[256];
  int tid = threadIdx.x;
  cnt[tid] = 0;
  deg[tid] = 0.f;
  __syncthreads();
  int fill = gcur[b];
  const u64* w = bkt + (size_t)b * BCAP;
  for (int p = tid; p < fill; p += 256) {
    u64 v = w[p];
    uint_t cl = (uint_t)(v >> 56);
    float wv = __uint_as_float((uint_t)(v & 0xffffffffULL));
    atomicAdd(&cnt[cl], 1u);
    atomicAdd(&deg[cl], wv);
  }
  __syncthreads();
  int pc = ((int)cnt[tid] + 7) & ~7;  // padded count
  ssc[tid] = pc;
  __syncthreads();
  for (int off = 1; off < 256; off <<= 1) {
    int u = (tid >= off) ? ssc[tid - off] : 0;
    __syncthreads();
    ssc[tid] += u;
    __syncthreads();
  }
  int node = (b << 8) + tid;
  if (node < n) {
    start[node] = ssc[tid] - pc;  // LOCAL padded offset within bucket
    float d = deg[tid];
    dinv[node] = d > 0.f ? rsqrtf(fmaxf(d, 1e-12f)) : 0.f;
  }
  if (tid == 255) pbs[b] = ssc[255];  // bucket padded total
}

// exclusive scan of bucket padded totals -> pbase; sentinel start[n] = total
__global__ void scan_pb(const int* __restrict__ pbs, int* __restrict__ pbase,
                        int* __restrict__ start, int nbk, int n) {
  __shared__ int s[512];
  int t = threadIdx.x;
  int v = (t < nbk) ? pbs[t] : 0;
  s[t] = v;
  __syncthreads();
  for (int off = 1; off < 512; off <<= 1) {
    int u = (t >= off) ? s[t - off] : 0;
    __syncthreads();
    s[t] += u;
    __syncthreads();
  }
  if (t < nbk) pbase[t] = s[t] - v;
  if (t == 0) {
    pbase[nbk] = s[nbk - 1 < 512 ? nbk - 1 : 511];
    start[n] = pbase[nbk];
  }
}

// per-bucket: finalize start[] (local + pbase), emit meta {r, nrm}, write pads.
__global__ __launch_bounds__(256) void bucket_emit(
    const u64* __restrict__ bkt, const int* __restrict__ gcur, const int* __restrict__ pbase,
    int* __restrict__ start, const float* __restrict__ dinv, u32x2* __restrict__ meta, int n) {
  int b = blockIdx.x;
  __shared__ uint_t lcur[256];
  __shared__ int sstart[256];
  int tid = threadIdx.x;
  int node = (b << 8) + tid;
  int bb = pbase[b];
  int fin = 0;
  if (node < n) {
    fin = start[node] + bb;
    sstart[tid] = fin;
  }
  lcur[tid] = 0;
  __syncthreads();
  int fill = gcur[b];
  const u64* w = bkt + (size_t)b * BCAP;
  for (int p = tid; p < fill; p += 256) {
    u64 v = w[p];
    uint_t hi = (uint_t)(v >> 32);
    uint_t r = hi & 0xffffffu;
    uint_t cl = hi >> 24;
    float wv = __uint_as_float((uint_t)(v & 0xffffffffULL));
    uint_t nd = ((uint_t)b << 8) + cl;
    float nrm = dinv[r] * wv * dinv[nd];
    uint_t slot = (uint_t)sstart[cl] + atomicAdd(&lcur[cl], 1u);
    u32x2 m;
    m.x = r;
    m.y = __float_as_uint(nrm);
    meta[slot] = m;
  }
  __syncthreads();
  if (node < n) {
    start[node] = fin;  // finalize for SpMM
    int c = (int)lcur[tid];
    int pc = (c + 7) & ~7;
    u32x2 z;
    z.x = 0u;
    z.y = 0u;
    for (int i = c; i < pc; ++i) meta[fin + i] = z;  // pad entries
  }
}

// ---------------- fused small prep: convert_x + 3 W swizzles ----------------
// W swizzle out layout: [t (global kstep)][j 0..7][lane 0..63][i 0..7] bf16
// fragment element = B[k][col], k = 32*t_in_src + 8*(lane>>4) + i, col = 16*j + (lane&15)
__global__ __launch_bounds__(256) void prep_misc(
    const float* __restrict__ x, uint_t* __restrict__ x32,
    const float* __restrict__ W1, ushort_t* __restrict__ Wz1,
    const float* __restrict__ W2, ushort_t* __restrict__ Wz2,
    const float* __restrict__ W3, ushort_t* __restrict__ Wz3, int n, int gconv) {
  int blk = blockIdx.x;
  int tid = threadIdx.x;
  if (blk < gconv) {
    // x (n x 26 fp32) -> padded bf16 (n x 32)
    int idx = blk * 256 + tid;
    if (idx >= n * 16) return;
    int node = idx >> 4, lane = idx & 15;
    float f0 = 0.f, f1 = 0.f;
    if (lane < 13) {
      f0 = x[node * 26 + 2 * lane];
      f1 = x[node * 26 + 2 * lane + 1];
    }
    x32[idx] = pack2(f0, f1);
  } else if (blk < gconv + 64) {
    // W1 kcat: ksps=1, kwv=26, nsrc=4
    int idx = (blk - gconv) * 256 + tid;
    int i = idx & 7, l = (idx >> 3) & 63, j = (idx >> 9) & 7, t = idx >> 12;
    int k = 8 * (l >> 4) + i;
    int col = 16 * j + (l & 15);
    float v = (k < NCLS) ? W1[((size_t)t * NCLS + k) * 128 + col] : 0.f;
    Wz1[idx] = f2b(v);
  } else if (blk < gconv + 64 + 256) {
    // W2 kcat: ksps=4, kwv=128, nsrc=4
    int idx = (blk - gconv - 64) * 256 + tid;
    int i = idx & 7, l = (idx >> 3) & 63, j = (idx >> 9) & 7, t = idx >> 12;
    int s = t >> 2, tt = t & 3;
    int k = tt * 32 + 8 * (l >> 4) + i;
    int col = 16 * j + (l & 15);
    float v = W2[((size_t)s * HID + k) * 128 + col];
    Wz2[idx] = f2b(v);
  } else {
    // W3 nslot
    int idx = (blk - gconv - 64 - 256) * 256 + tid;
    int i = idx & 7, l = (idx >> 3) & 63, j = (idx >> 9) & 7, t = idx >> 12;
    int k = t * 32 + 8 * (l >> 4) + i;
    int col = 16 * j + (l & 15);
    int s = col >> 5, c = col & 31;
    float v = (c < 26) ? W3[((size_t)s * 128 + k) * 26 + c] : 0.f;
    Wz3[idx] = f2b(v);
  }
}

// ---------------- SpMM (pull, padded CSR, bf16, interleaved meta) ----------------
// mp = start[node+1]-start[node] is a multiple of 8; pad entries have weight 0
// and row 0 -> inner loops have NO bounds logic (only prefetch-index clamps).

// width 128: wave per node; 16 lanes per edge-slot (eq), dwordx4 gathers;
// meta prefetched 2 iterations ahead, gathered VALUES 1 iteration ahead.
__global__ __launch_bounds__(256) void spmm128_bf(
    const u32x2* __restrict__ meta, const int* __restrict__ start,
    const uint_t* __restrict__ in, uint_t* __restrict__ out, int n) {
  int node = blockIdx.x * 4 + (threadIdx.x >> 6);
  int lane = threadIdx.x & 63;
  if (node >= n) return;
  int s = start[node], mp = start[node + 1] - s;
  int eq = lane >> 4;
  uint_t foff = (uint_t)(lane & 15) << 4;  // byte offset within 256B row
  const char* inb = (const char*)in;
  float a0 = 0.f, a1 = 0.f, a2 = 0.f, a3 = 0.f, a4 = 0.f, a5 = 0.f, a6 = 0.f, a7 = 0.f;
  if (mp > 0) {
    u32x2 mtA0 = meta[s + eq];
    u32x2 mtA1 = meta[s + 4 + eq];
    int i8 = 8 + eq;
    if (i8 >= mp) i8 = mp - 1;
    int i12 = 12 + eq;
    if (i12 >= mp) i12 = mp - 1;
    u32x2 mtB0 = meta[s + i8];
    u32x2 mtB1 = meta[s + i12];
    u32x4 vA0 = *reinterpret_cast<const u32x4*>(inb + (((uint_t)mtA0.x << 8) + foff));
    u32x4 vA1 = *reinterpret_cast<const u32x4*>(inb + (((uint_t)mtA1.x << 8) + foff));
    for (int base = 0; base < mp; base += 8) {
      int p0 = base + 16 + eq;
      p0 = p0 < mp ? p0 : mp - 1;
      int p1 = base + 20 + eq;
      p1 = p1 < mp ? p1 : mp - 1;
      u32x2 mtC0 = meta[s + p0];
      u32x2 mtC1 = meta[s + p1];
      u32x4 vB0 = *reinterpret_cast<const u32x4*>(inb + (((uint_t)mtB0.x << 8) + foff));
      u32x4 vB1 = *reinterpret_cast<const u32x4*>(inb + (((uint_t)mtB1.x << 8) + foff));
      float w0 = __uint_as_float(mtA0.y);
      float w1 = __uint_as_float(mtA1.y);
      a0 += w0 * lo16(vA0.x); a1 += w0 * hi16(vA0.x);
      a2 += w0 * lo16(vA0.y); a3 += w0 * hi16(vA0.y);
      a4 += w0 * lo16(vA0.z); a5 += w0 * hi16(vA0.z);
      a6 += w0 * lo16(vA0.w); a7 += w0 * hi16(vA0.w);
      a0 += w1 * lo16(vA1.x); a1 += w1 * hi16(vA1.x);
      a2 += w1 * lo16(vA1.y); a3 += w1 * hi16(vA1.y);
      a4 += w1 * lo16(vA1.z); a5 += w1 * hi16(vA1.z);
      a6 += w1 * lo16(vA1.w); a7 += w1 * hi16(vA1.w);
      mtA0 = mtB0; mtA1 = mtB1;
      mtB0 = mtC0; mtB1 = mtC1;
      vA0 = vB0; vA1 = vB1;
    }
  }
  a0 += __shfl_xor(a0, 16); a1 += __shfl_xor(a1, 16);
  a2 += __shfl_xor(a2, 16); a3 += __shfl_xor(a3, 16);
  a4 += __shfl_xor(a4, 16); a5 += __shfl_xor(a5, 16);
  a6 += __shfl_xor(a6, 16); a7 += __shfl_xor(a7, 16);
  a0 += __shfl_xor(a0, 32); a1 += __shfl_xor(a1, 32);
  a2 += __shfl_xor(a2, 32); a3 += __shfl_xor(a3, 32);
  a4 += __shfl_xor(a4, 32); a5 += __shfl_xor(a5, 32);
  a6 += __shfl_xor(a6, 32); a7 += __shfl_xor(a7, 32);
  if (eq == 0) {
    u32x4 o;
    o.x = pack2(a0, a1);
    o.y = pack2(a2, a3);
    o.z = pack2(a4, a5);
    o.w = pack2(a6, a7);
    *reinterpret_cast<u32x4*>(out + (size_t)node * 64 + (foff >> 2)) = o;
  }
}

// width 32-padded: 8 lanes per node (dwordx2 each); cooperative meta load with
// chunk-level value double-buffer: chunk i+1's meta + 8 gathers issue while
// chunk i's FMAs run -> 64 value-gathers in flight per wave.
__global__ __launch_bounds__(256) void spmm26_bf(
    const u32x2* __restrict__ meta, const int* __restrict__ start,
    const uint_t* __restrict__ in, const uint_t* __restrict__ add,
    uint_t* __restrict__ out, int n) {
  int node = blockIdx.x * 32 + (threadIdx.x >> 3);
  int ln = threadIdx.x & 7;
  if (node >= n) return;
  int s = start[node], mp = start[node + 1] - s;
  uint_t foff = (uint_t)ln << 3;  // byte offset within 64B row
  const char* inb = (const char*)in;
  float a0 = 0.f, a1 = 0.f, a2 = 0.f, a3 = 0.f;
  if (mp > 0) {
    u32x2 mtA = meta[s + ln];
    u32x2 vA[8];
#pragma unroll
    for (int k = 0; k < 8; ++k) {
      uint_t r = (uint_t)__shfl((int)mtA.x, k, 8);
      vA[k] = *reinterpret_cast<const u32x2*>(inb + ((r << 6) + foff));
    }
    for (int base = 0; base < mp; base += 8) {
      int nx = base + 8 + ln;
      nx = nx < mp ? nx : mp - 1;
      u32x2 mtB = meta[s + nx];
      u32x2 vB[8];
#pragma unroll
      for (int k = 0; k < 8; ++k) {
        uint_t r = (uint_t)__shfl((int)mtB.x, k, 8);
        vB[k] = *reinterpret_cast<const u32x2*>(inb + ((r << 6) + foff));
      }
#pragma unroll
      for (int k = 0; k < 8; ++k) {
        float wv = __uint_as_float((uint_t)__shfl((int)mtA.y, k, 8));
        a0 += wv * lo16(vA[k].x); a1 += wv * hi16(vA[k].x);
        a2 += wv * lo16(vA[k].y); a3 += wv * hi16(vA[k].y);
      }
      mtA = mtB;
#pragma unroll
      for (int k = 0; k < 8; ++k) vA[k] = vB[k];
    }
  }
  if (add) {
    u32x2 v = *reinterpret_cast<const u32x2*>(add + (size_t)node * 16 + 2 * ln);
    a0 += lo16(v.x); a1 += hi16(v.x);
    a2 += lo16(v.y); a3 += hi16(v.y);
  }
  u32x2 o;
  o.x = pack2(a0, a1);
  o.y = pack2(a2, a3);
  *reinterpret_cast<u32x2*>(out + (size_t)node * 16 + 2 * ln) = o;
}

// final Horner step: out_f32 (n x 26) += A*in  (same double-buffered structure)
__global__ __launch_bounds__(256) void spmm26_addf(
    const u32x2* __restrict__ meta, const int* __restrict__ start,
    const uint_t* __restrict__ in, float* __restrict__ out, int n) {
  int node = blockIdx.x * 32 + (threadIdx.x >> 3);
  int ln = threadIdx.x & 7;
  if (node >= n) return;
  int s = start[node], mp = start[node + 1] - s;
  uint_t foff = (uint_t)ln << 3;
  const char* inb = (const char*)in;
  float a0 = 0.f, a1 = 0.f, a2 = 0.f, a3 = 0.f;
  if (mp > 0) {
    u32x2 mtA = meta[s + ln];
    u32x2 vA[8];
#pragma unroll
    for (int k = 0; k < 8; ++k) {
      uint_t r = (uint_t)__shfl((int)mtA.x, k, 8);
      vA[k] = *reinterpret_cast<const u32x2*>(inb + ((r << 6) + foff));
    }
    for (int base = 0; base < mp; base += 8) {
      int nx = base + 8 + ln;
      nx = nx < mp ? nx : mp - 1;
      u32x2 mtB = meta[s + nx];
      u32x2 vB[8];
#pragma unroll
      for (int k = 0; k < 8; ++k) {
        uint_t r = (uint_t)__shfl((int)mtB.x, k, 8);
        vB[k] = *reinterpret_cast<const u32x2*>(inb + ((r << 6) + foff));
      }
#pragma unroll
      for (int k = 0; k < 8; ++k) {
        float wv = __uint_as_float((uint_t)__shfl((int)mtA.y, k, 8));
        a0 += wv * lo16(vA[k].x); a1 += wv * hi16(vA[k].x);
        a2 += wv * lo16(vA[k].y); a3 += wv * hi16(vA[k].y);
      }
      mtA = mtB;
#pragma unroll
      for (int k = 0; k < 8; ++k) vA[k] = vB[k];
    }
  }
  int c0 = 4 * ln;
  if (c0 + 0 < 26) out[(size_t)node * 26 + c0 + 0] += a0;
  if (c0 + 1 < 26) out[(size_t)node * 26 + c0 + 1] += a1;
  if (c0 + 2 < 26) out[(size_t)node * 26 + c0 + 2] += a2;
  if (c0 + 3 < 26) out[(size_t)node * 26 + c0 + 3] += a3;
}

// ---------------- fused MFMA GEMM: double-buffered LDS W, 1 barrier/group ----------------
// C(n x 128) = [A0|A1|A2|A3] (each n x KW bf16) @ Wswz (+bias)
// Per group g: [issue loads g+1] -> [compute sW[g&1]] -> [write sW[(g+1)&1]] -> barrier.
// EPI 0: ELU, write bf16 n x 128 to outb
// EPI 1: layer-3 slots: slot0 -> outf (n x 26 fp32, +bias); slots 1..3 -> outb (3 x n x 32 bf16)
template <int KW, int NSRC, int EPI, int GROUP>
__global__ __launch_bounds__(256) void mfma_gemm(
    const ushort_t* __restrict__ A0, const ushort_t* __restrict__ A1,
    const ushort_t* __restrict__ A2, const ushort_t* __restrict__ A3,
    const ushort_t* __restrict__ Wswz, const float* __restrict__ bias,
    ushort_t* __restrict__ outb, float* __restrict__ outf, int n) {
  constexpr int KSPS = KW / 32;
  constexpr int KSTEPS = NSRC * KSPS;
  constexpr int NGROUPS = KSTEPS / GROUP;
  __shared__ ushort_t sW[2][GROUP * 4096];
  const int tid = threadIdx.x;
  const int w = tid >> 6;
  const int l = tid & 63;
  const int row0 = blockIdx.x * 64 + w * 16;
  const int koff = 8 * (l >> 4);  // elements
  const int arow = row0 + (l & 15);
  const int arow_c = arow < n ? arow : (n - 1);

  f32x4 acc[8];
#pragma unroll
  for (int j = 0; j < 8; ++j) acc[j] = (f32x4){0.f, 0.f, 0.f, 0.f};

  const ushort_t* const srcs[4] = {A0, A1, A2, A3};

  auto aload = [&](int t) {
    const int s = t / KSPS;
    const int tt = t - s * KSPS;
    return ld_frag(srcs[s] + (size_t)arow_c * KW + tt * 32 + koff);
  };

  // parity register sets: even groups use afA/gwA, odd use afB/gwB
  bf16x8 afA[GROUP], afB[GROUP];
  u32x4 gwA[2 * GROUP], gwB[2 * GROUP];

  // prologue: load group 0 (A + W), write sW[0], barrier
#pragma unroll
  for (int c = 0; c < GROUP; ++c) {
    afA[c] = aload(c);
    const ushort_t* p = Wswz + (size_t)c * 4096 + tid * 8;
    gwA[2 * c] = *reinterpret_cast<const u32x4*>(p);
    gwA[2 * c + 1] = *reinterpret_cast<const u32x4*>(p + 2048);
  }
#pragma unroll
  for (int c = 0; c < GROUP; ++c) {
    *reinterpret_cast<u32x4*>(&sW[0][c * 4096 + tid * 8]) = gwA[2 * c];
    *reinterpret_cast<u32x4*>(&sW[0][c * 4096 + tid * 8 + 2048]) = gwA[2 * c + 1];
  }
  __syncthreads();

#pragma unroll
  for (int g = 0; g < NGROUPS; ++g) {
    const bool even = (g & 1) == 0;
    // issue next group's loads into the opposite register set
    if (g + 1 < NGROUPS) {
#pragma unroll
      for (int c = 0; c < GROUP; ++c) {
        const ushort_t* p = Wswz + (size_t)(g + 1) * GROUP * 4096 + (size_t)c * 4096 + tid * 8;
        if (even) {
          gwB[2 * c] = *reinterpret_cast<const u32x4*>(p);
          gwB[2 * c + 1] = *reinterpret_cast<const u32x4*>(p + 2048);
          afB[c] = aload((g + 1) * GROUP + c);
        } else {
          gwA[2 * c] = *reinterpret_cast<const u32x4*>(p);
          gwA[2 * c + 1] = *reinterpret_cast<const u32x4*>(p + 2048);
          afA[c] = aload((g + 1) * GROUP + c);
        }
      }
    }
    // compute current group from sW[g&1]
#pragma unroll
    for (int tg = 0; tg < GROUP; ++tg) {
      bf16x8 af = even ? afA[tg] : afB[tg];
      const ushort_t* wp = &sW[g & 1][tg * 4096 + l * 8];
#pragma unroll
      for (int j = 0; j < 8; ++j) {
        bf16x8 bfr = ld_frag(wp + j * 64 * 8);
        acc[j] = __builtin_amdgcn_mfma_f32_16x16x32_bf16(af, bfr, acc[j], 0, 0, 0);
      }
    }
    // write next group's W into the other LDS buffer (waitcnt overlapped with MFMAs above)
    if (g + 1 < NGROUPS) {
#pragma unroll
      for (int c = 0; c < GROUP; ++c) {
        u32x4 lo = even ? gwB[2 * c] : gwA[2 * c];
        u32x4 hi = even ? gwB[2 * c + 1] : gwA[2 * c + 1];
        *reinterpret_cast<u32x4*>(&sW[(g + 1) & 1][c * 4096 + tid * 8]) = lo;
        *reinterpret_cast<u32x4*>(&sW[(g + 1) & 1][c * 4096 + tid * 8 + 2048]) = hi;
      }
    }
    __syncthreads();
  }

  const int ccol = l & 15;
  const int crow0 = row0 + 4 * (l >> 4);
#pragma unroll
  for (int j = 0; j < 8; ++j) {
    if (EPI == 0) {
      int col = 16 * j + ccol;
      float bi = bias[col];
#pragma unroll
      for (int r = 0; r < 4; ++r) {
        int row = crow0 + r;
        if (row >= n) continue;
        float v = acc[j][r] + bi;
        v = v > 0.f ? v : (__expf(v) - 1.f);
        outb[(size_t)row * 128 + col] = f2b(v);
      }
    } else {
      int slot = j >> 1;
      int c = 16 * (j & 1) + ccol;
#pragma unroll
      for (int r = 0; r < 4; ++r) {
        int row = crow0 + r;
        if (row >= n) continue;
        float v = acc[j][r];
        if (slot == 0) {
          if (c < 26) outf[(size_t)row * 26 + c] = v + bias[c];
        } else {
          outb[((size_t)(slot - 1) * n + row) * 32 + c] = f2b(v);
        }
      }
    }
  }
}

// ---------------- launcher ----------------

extern "C" void kernel_launch(void* const* d_in, const int* in_sizes, int n_in,
                              void* d_out, int out_size, void* d_ws, size_t ws_size,
                              hipStream_t stream) {
  const float* x  = (const float*)d_in[0];
  const int*   ei = (const int*)d_in[1];
  const float* ew = (const float*)d_in[2];
  const float* W1 = (const float*)d_in[3];
  const float* b1 = (const float*)d_in[4];
  const float* W2 = (const float*)d_in[5];
  const float* b2 = (const float*)d_in[6];
  const float* W3 = (const float*)d_in[7];
  const float* b3 = (const float*)d_in[8];
  float* out = (float*)d_out;

  const int n = in_sizes[0] / NCLS;  // 100000
  const int E = in_sizes[2];         // 1600000
  const int nbk = (n + 255) >> 8;    // 391 buckets

  char* w = (char*)d_ws;
  auto alloc = [&](size_t bytes) {
    char* p = w;
    w += (bytes + 255) / 256 * 256;
    return p;
  };
  // width-128 bf16 feature buffers (64 dwords per node)
  uint_t* H0 = (uint_t*)alloc((size_t)n * 64 * 4);
  uint_t* P1 = (uint_t*)alloc((size_t)n * 64 * 4);
  uint_t* P2 = (uint_t*)alloc((size_t)n * 64 * 4);
  uint_t* P3 = (uint_t*)alloc((size_t)n * 64 * 4);
  uint_t* H1 = (uint_t*)alloc((size_t)n * 64 * 4);
  // width-32-padded bf16 buffers (16 dwords per node)
  uint_t* x32 = (uint_t*)alloc((size_t)n * 16 * 4);
  uint_t* q1  = (uint_t*)alloc((size_t)n * 16 * 4);
  uint_t* q2  = (uint_t*)alloc((size_t)n * 16 * 4);
  uint_t* q3  = (uint_t*)alloc((size_t)n * 16 * 4);
  uint_t* zb  = (uint_t*)alloc((size_t)n * 48 * 4);  // z1,z2,z3 each n x 32 bf16
  // swizzled weights
  ushort_t* Wz1 = (ushort_t*)alloc(4 * 4096 * 2);
  ushort_t* Wz2 = (ushort_t*)alloc(16 * 4096 * 2);
  ushort_t* Wz3 = (ushort_t*)alloc(4 * 4096 * 2);
  // graph CSR (padded)
  u64*   bkt  = (u64*)zb;  // alias: bkt (18.8MB @ BCAP=6016) dead before zb (19.2MB) is used
  u32x2* meta = (u32x2*)alloc(((size_t)E + 7 * (size_t)n + 64) * 8);
  int*   start = (int*)alloc((size_t)(n + 1) * 4);
  float* dinv  = (float*)alloc((size_t)n * 4);
  int*   gcur  = (int*)alloc(MAXBK * 4);
  int*   pbs   = (int*)alloc(MAXBK * 4);
  int*   pbase = (int*)alloc((MAXBK + 1) * 4);

  const int ab = (E + EPB - 1) / EPB;  // bucketing blocks (196)
  const int gconv = (n * 16 + 255) / 256;

  // independent small prep (x conversion + W swizzles) in one launch
  prep_misc<<<gconv + 64 + 256 + 64, 256, 0, stream>>>(x, x32, W1, Wz1, W2, Wz2, W3, Wz3,
                                                       n, gconv);

  hipMemsetAsync(gcur, 0, MAXBK * 4, stream);
  bucket_place<<<ab, 256, 0, stream>>>(ei, ew, gcur, bkt, E, nbk);
  bucket_stats<<<nbk, 256, 0, stream>>>(bkt, gcur, start, pbs, dinv, n);
  scan_pb<<<1, 512, 0, stream>>>(pbs, pbase, start, nbk, n);
  bucket_emit<<<nbk, 256, 0, stream>>>(bkt, gcur, pbase, start, dinv, meta, n);

  const int g128 = (n + 3) / 4;
  const int g26  = (n + 31) / 32;
  const int gg   = (n + 63) / 64;  // mfma_gemm grid (64 rows/block)

  // ---- Layer 1: q_k = A^k x (width 32-padded), H0 = ELU([x|q1|q2|q3] @ W1cat + b1) ----
  spmm26_bf<<<g26, 256, 0, stream>>>(meta, start, x32, nullptr, q1, n);
  spmm26_bf<<<g26, 256, 0, stream>>>(meta, start, q1, nullptr, q2, n);
  spmm26_bf<<<g26, 256, 0, stream>>>(meta, start, q2, nullptr, q3, n);
  mfma_gemm<32, 4, 0, 2><<<gg, 256, 0, stream>>>(
      (const ushort_t*)x32, (const ushort_t*)q1, (const ushort_t*)q2, (const ushort_t*)q3,
      Wz1, b1, (ushort_t*)H0, nullptr, n);

  // ---- Layer 2: P_k = A^k H0, H1 = ELU([H0|P1|P2|P3] @ W2cat + b2) ----
  spmm128_bf<<<g128, 256, 0, stream>>>(meta, start, H0, P1, n);
  spmm128_bf<<<g128, 256, 0, stream>>>(meta, start, P1, P2, n);
  spmm128_bf<<<g128, 256, 0, stream>>>(meta, start, P2, P3, n);
  mfma_gemm<128, 4, 0, 2><<<gg, 256, 0, stream>>>(
      (const ushort_t*)H0, (const ushort_t*)P1, (const ushort_t*)P2, (const ushort_t*)P3,
      Wz2, b2, (ushort_t*)H1, nullptr, n);

  // ---- Layer 3: Z = H1 @ [W3_0|W3_1|W3_2|W3_3]; Horner out = z0+b3 + A(z1 + A(z2 + A z3)) ----
  // NOTE: zb aliases bkt, which is dead after bucket_emit — safe.
  mfma_gemm<128, 1, 1, 2><<<gg, 256, 0, stream>>>(
      (const ushort_t*)H1, (const ushort_t*)H1, (const ushort_t*)H1, (const ushort_t*)H1,
      Wz3, b3, (ushort_t*)zb, out, n);

  uint_t* z1 = zb;
  uint_t* z2 = zb + (size_t)n * 16;
  uint_t* z3 = zb + (size_t)n * 32;
  spmm26_bf<<<g26, 256, 0, stream>>>(meta, start, z3, z2, q1, n);  // q1 = z2 + A z3
  spmm26_bf<<<g26, 256, 0, stream>>>(meta, start, q1, z1, q2, n);  // q2 = z1 + A q1
  spmm26_addf<<<g26, 256, 0, stream>>>(meta, start, q2, out, n);   // out += A q2
}

// Round 17
// 450.069 us; speedup vs baseline: 1.0263x; 1.0263x over previous
//
#include <hip/hip_runtime.h>

#define NCLS 26
#define HID 128
#define EPB 8192   // edges per bucketing block
#define MAXBK 512  // max buckets (supports n <= 131072)
#define BCAP 6016  // fixed bucket capacity (mean 4092 + ~30 sigma for uniform input)
typedef unsigned short ushort_t;
typedef unsigned int uint_t;
typedef unsigned long long u64;

typedef __bf16 bf16x8 __attribute__((ext_vector_type(8)));
typedef float f32x4 __attribute__((ext_vector_type(4)));
typedef unsigned int u32x4 __attribute__((ext_vector_type(4)));
typedef unsigned int u32x2 __attribute__((ext_vector_type(2)));

// ---------------- bf16 helpers (ushort storage) ----------------
static __device__ __forceinline__ float b2f(ushort_t h) {
  return __uint_as_float(((uint_t)h) << 16);
}
static __device__ __forceinline__ ushort_t f2b(float f) {
  uint_t u = __float_as_uint(f);
  uint_t r = (u + 0x7fffu + ((u >> 16) & 1u)) >> 16;
  return (ushort_t)r;
}
static __device__ __forceinline__ uint_t pack2(float f0, float f1) {
  return (uint_t)f2b(f0) | ((uint_t)f2b(f1) << 16);
}
static __device__ __forceinline__ float lo16(uint_t v) { return b2f((ushort_t)(v & 0xffffu)); }
static __device__ __forceinline__ float hi16(uint_t v) { return b2f((ushort_t)(v >> 16)); }
static __device__ __forceinline__ bf16x8 ld_frag(const ushort_t* p) {
  u32x4 v = *reinterpret_cast<const u32x4*>(p);
  return __builtin_bit_cast(bf16x8, v);
}

// ---------------- preprocessing: two-level bucket sort, PADDED CSR ----------------
// bucket(c) = c >> 8 (256 nodes per bucket). Packed bucket record (u64):
// hi32 = r | (c_local << 24), lo32 = fp32 weight bits.
// Buckets live at fixed offsets b*BCAP in bkt; gcur[b] = fill count.
// Each node's meta list is padded to a multiple of 8 with {row 0, weight 0}
// entries so the SpMM inner loops need NO per-edge bounds logic.

__global__ __launch_bounds__(256) void bucket_place(
    const int* __restrict__ ei, const float* __restrict__ ew,
    int* __restrict__ gcur, u64* __restrict__ bkt, int E, int nbk) {
  __shared__ uint_t lc[MAXBK];
  __shared__ uint_t lb[MAXBK];
  int tid = threadIdx.x;
  for (int t = tid; t < nbk; t += 256) lc[t] = 0;
  __syncthreads();
  int e0 = blockIdx.x * EPB;
#pragma unroll
  for (int i = 0; i < EPB / 256; ++i) {
    int e = e0 + tid + i * 256;
    if (e < E) atomicAdd(&lc[(uint_t)ei[E + e] >> 8], 1u);
  }
  __syncthreads();
  for (int t = tid; t < nbk; t += 256) {
    uint_t c = lc[t];
    lb[t] = c ? (uint_t)t * BCAP + (uint_t)atomicAdd(&gcur[t], (int)c) : 0u;
    lc[t] = 0;
  }
  __syncthreads();
#pragma unroll
  for (int i = 0; i < EPB / 256; ++i) {
    int e = e0 + tid + i * 256;
    if (e < E) {
      uint_t r = (uint_t)ei[e];
      uint_t c = (uint_t)ei[E + e];
      uint_t b = c >> 8;
      uint_t pos = lb[b] + atomicAdd(&lc[b], 1u);
      bkt[pos] = ((u64)(r | ((c & 255u) << 24)) << 32) | (u64)__float_as_uint(ew[e]);
    }
  }
}

// per-bucket: LDS count + weighted degree; scan of PADDED counts -> local starts
// (written to start[]), bucket padded totals -> pbs[]; dinv[].
__global__ __launch_bounds__(256) void bucket_stats(
    const u64* __restrict__ bkt, const int* __restrict__ gcur,
    int* __restrict__ start, int* __restrict__ pbs, float* __restrict__ dinv, int n) {
  int b = blockIdx.x;
  __shared__ uint_t cnt[256];
  __shared__ float deg[256];
  __shared__ int ssc[256];
  int tid = threadIdx.x;
  cnt[tid] = 0;
  deg[tid] = 0.f;
  __syncthreads();
  int fill = gcur[b];
  const u64* w = bkt + (size_t)b * BCAP;
  for (int p = tid; p < fill; p += 256) {
    u64 v = w[p];
    uint_t cl = (uint_t)(v >> 56);
    float wv = __uint_as_float((uint_t)(v & 0xffffffffULL));
    atomicAdd(&cnt[cl], 1u);
    atomicAdd(&deg[cl], wv);
  }
  __syncthreads();
  int pc = ((int)cnt[tid] + 7) & ~7;  // padded count
  ssc[tid] = pc;
  __syncthreads();
  for (int off = 1; off < 256; off <<= 1) {
    int u = (tid >= off) ? ssc[tid - off] : 0;
    __syncthreads();
    ssc[tid] += u;
    __syncthreads();
  }
  int node = (b << 8) + tid;
  if (node < n) {
    start[node] = ssc[tid] - pc;  // LOCAL padded offset within bucket
    float d = deg[tid];
    dinv[node] = d > 0.f ? rsqrtf(fmaxf(d, 1e-12f)) : 0.f;
  }
  if (tid == 255) pbs[b] = ssc[255];  // bucket padded total
}

// exclusive scan of bucket padded totals -> pbase; sentinel start[n] = total
__global__ void scan_pb(const int* __restrict__ pbs, int* __restrict__ pbase,
                        int* __restrict__ start, int nbk, int n) {
  __shared__ int s[512];
  int t = threadIdx.x;
  int v = (t < nbk) ? pbs[t] : 0;
  s[t] = v;
  __syncthreads();
  for (int off = 1; off < 512; off <<= 1) {
    int u = (t >= off) ? s[t - off] : 0;
    __syncthreads();
    s[t] += u;
    __syncthreads();
  }
  if (t < nbk) pbase[t] = s[t] - v;
  if (t == 0) {
    pbase[nbk] = s[nbk - 1 < 512 ? nbk - 1 : 511];
    start[n] = pbase[nbk];
  }
}

// per-bucket: finalize start[] (local + pbase), emit meta {r, nrm}, write pads.
__global__ __launch_bounds__(256) void bucket_emit(
    const u64* __restrict__ bkt, const int* __restrict__ gcur, const int* __restrict__ pbase,
    int* __restrict__ start, const float* __restrict__ dinv, u32x2* __restrict__ meta, int n) {
  int b = blockIdx.x;
  __shared__ uint_t lcur[256];
  __shared__ int sstart[256];
  int tid = threadIdx.x;
  int node = (b << 8) + tid;
  int bb = pbase[b];
  int fin = 0;
  if (node < n) {
    fin = start[node] + bb;
    sstart[tid] = fin;
  }
  lcur[tid] = 0;
  __syncthreads();
  int fill = gcur[b];
  const u64* w = bkt + (size_t)b * BCAP;
  for (int p = tid; p < fill; p += 256) {
    u64 v = w[p];
    uint_t hi = (uint_t)(v >> 32);
    uint_t r = hi & 0xffffffu;
    uint_t cl = hi >> 24;
    float wv = __uint_as_float((uint_t)(v & 0xffffffffULL));
    uint_t nd = ((uint_t)b << 8) + cl;
    float nrm = dinv[r] * wv * dinv[nd];
    uint_t slot = (uint_t)sstart[cl] + atomicAdd(&lcur[cl], 1u);
    u32x2 m;
    m.x = r;
    m.y = __float_as_uint(nrm);
    meta[slot] = m;
  }
  __syncthreads();
  if (node < n) {
    start[node] = fin;  // finalize for SpMM
    int c = (int)lcur[tid];
    int pc = (c + 7) & ~7;
    u32x2 z;
    z.x = 0u;
    z.y = 0u;
    for (int i = c; i < pc; ++i) meta[fin + i] = z;  // pad entries
  }
}

// ---------------- fused small prep: convert_x + 3 W swizzles ----------------
// W swizzle out layout: [t (global kstep)][j 0..7][lane 0..63][i 0..7] bf16
// fragment element = B[k][col], k = 32*t_in_src + 8*(lane>>4) + i, col = 16*j + (lane&15)
__global__ __launch_bounds__(256) void prep_misc(
    const float* __restrict__ x, uint_t* __restrict__ x32,
    const float* __restrict__ W1, ushort_t* __restrict__ Wz1,
    const float* __restrict__ W2, ushort_t* __restrict__ Wz2,
    const float* __restrict__ W3, ushort_t* __restrict__ Wz3, int n, int gconv) {
  int blk = blockIdx.x;
  int tid = threadIdx.x;
  if (blk < gconv) {
    // x (n x 26 fp32) -> padded bf16 (n x 32)
    int idx = blk * 256 + tid;
    if (idx >= n * 16) return;
    int node = idx >> 4, lane = idx & 15;
    float f0 = 0.f, f1 = 0.f;
    if (lane < 13) {
      f0 = x[node * 26 + 2 * lane];
      f1 = x[node * 26 + 2 * lane + 1];
    }
    x32[idx] = pack2(f0, f1);
  } else if (blk < gconv + 64) {
    // W1 kcat: ksps=1, kwv=26, nsrc=4
    int idx = (blk - gconv) * 256 + tid;
    int i = idx & 7, l = (idx >> 3) & 63, j = (idx >> 9) & 7, t = idx >> 12;
    int k = 8 * (l >> 4) + i;
    int col = 16 * j + (l & 15);
    float v = (k < NCLS) ? W1[((size_t)t * NCLS + k) * 128 + col] : 0.f;
    Wz1[idx] = f2b(v);
  } else if (blk < gconv + 64 + 256) {
    // W2 kcat: ksps=4, kwv=128, nsrc=4
    int idx = (blk - gconv - 64) * 256 + tid;
    int i = idx & 7, l = (idx >> 3) & 63, j = (idx >> 9) & 7, t = idx >> 12;
    int s = t >> 2, tt = t & 3;
    int k = tt * 32 + 8 * (l >> 4) + i;
    int col = 16 * j + (l & 15);
    float v = W2[((size_t)s * HID + k) * 128 + col];
    Wz2[idx] = f2b(v);
  } else {
    // W3 nslot
    int idx = (blk - gconv - 64 - 256) * 256 + tid;
    int i = idx & 7, l = (idx >> 3) & 63, j = (idx >> 9) & 7, t = idx >> 12;
    int k = t * 32 + 8 * (l >> 4) + i;
    int col = 16 * j + (l & 15);
    int s = col >> 5, c = col & 31;
    float v = (c < 26) ? W3[((size_t)s * 128 + k) * 26 + c] : 0.f;
    Wz3[idx] = f2b(v);
  }
}

// ---------------- SpMM (pull, padded CSR, bf16, interleaved meta) ----------------
// mp = start[node+1]-start[node] is a multiple of 8; pad entries have weight 0
// and row 0 -> inner loops have NO bounds logic (only prefetch-index clamps).

// width 128: wave per node; 16 lanes per edge-slot (eq), dwordx4 gathers;
// meta prefetched 2 iterations ahead, gathered VALUES 1 iteration ahead.
__global__ __launch_bounds__(256) void spmm128_bf(
    const u32x2* __restrict__ meta, const int* __restrict__ start,
    const uint_t* __restrict__ in, uint_t* __restrict__ out, int n) {
  int node = blockIdx.x * 4 + (threadIdx.x >> 6);
  int lane = threadIdx.x & 63;
  if (node >= n) return;
  int s = start[node], mp = start[node + 1] - s;
  int eq = lane >> 4;
  uint_t foff = (uint_t)(lane & 15) << 4;  // byte offset within 256B row
  const char* inb = (const char*)in;
  float a0 = 0.f, a1 = 0.f, a2 = 0.f, a3 = 0.f, a4 = 0.f, a5 = 0.f, a6 = 0.f, a7 = 0.f;
  if (mp > 0) {
    u32x2 mtA0 = meta[s + eq];
    u32x2 mtA1 = meta[s + 4 + eq];
    int i8 = 8 + eq;
    if (i8 >= mp) i8 = mp - 1;
    int i12 = 12 + eq;
    if (i12 >= mp) i12 = mp - 1;
    u32x2 mtB0 = meta[s + i8];
    u32x2 mtB1 = meta[s + i12];
    u32x4 vA0 = *reinterpret_cast<const u32x4*>(inb + (((uint_t)mtA0.x << 8) + foff));
    u32x4 vA1 = *reinterpret_cast<const u32x4*>(inb + (((uint_t)mtA1.x << 8) + foff));
    for (int base = 0; base < mp; base += 8) {
      int p0 = base + 16 + eq;
      p0 = p0 < mp ? p0 : mp - 1;
      int p1 = base + 20 + eq;
      p1 = p1 < mp ? p1 : mp - 1;
      u32x2 mtC0 = meta[s + p0];
      u32x2 mtC1 = meta[s + p1];
      u32x4 vB0 = *reinterpret_cast<const u32x4*>(inb + (((uint_t)mtB0.x << 8) + foff));
      u32x4 vB1 = *reinterpret_cast<const u32x4*>(inb + (((uint_t)mtB1.x << 8) + foff));
      float w0 = __uint_as_float(mtA0.y);
      float w1 = __uint_as_float(mtA1.y);
      a0 += w0 * lo16(vA0.x); a1 += w0 * hi16(vA0.x);
      a2 += w0 * lo16(vA0.y); a3 += w0 * hi16(vA0.y);
      a4 += w0 * lo16(vA0.z); a5 += w0 * hi16(vA0.z);
      a6 += w0 * lo16(vA0.w); a7 += w0 * hi16(vA0.w);
      a0 += w1 * lo16(vA1.x); a1 += w1 * hi16(vA1.x);
      a2 += w1 * lo16(vA1.y); a3 += w1 * hi16(vA1.y);
      a4 += w1 * lo16(vA1.z); a5 += w1 * hi16(vA1.z);
      a6 += w1 * lo16(vA1.w); a7 += w1 * hi16(vA1.w);
      mtA0 = mtB0; mtA1 = mtB1;
      mtB0 = mtC0; mtB1 = mtC1;
      vA0 = vB0; vA1 = vB1;
    }
  }
  a0 += __shfl_xor(a0, 16); a1 += __shfl_xor(a1, 16);
  a2 += __shfl_xor(a2, 16); a3 += __shfl_xor(a3, 16);
  a4 += __shfl_xor(a4, 16); a5 += __shfl_xor(a5, 16);
  a6 += __shfl_xor(a6, 16); a7 += __shfl_xor(a7, 16);
  a0 += __shfl_xor(a0, 32); a1 += __shfl_xor(a1, 32);
  a2 += __shfl_xor(a2, 32); a3 += __shfl_xor(a3, 32);
  a4 += __shfl_xor(a4, 32); a5 += __shfl_xor(a5, 32);
  a6 += __shfl_xor(a6, 32); a7 += __shfl_xor(a7, 32);
  if (eq == 0) {
    u32x4 o;
    o.x = pack2(a0, a1);
    o.y = pack2(a2, a3);
    o.z = pack2(a4, a5);
    o.w = pack2(a6, a7);
    *reinterpret_cast<u32x4*>(out + (size_t)node * 64 + (foff >> 2)) = o;
  }
}

// width 32-padded: 8 lanes per node (dwordx2 each); cooperative meta load
// (8 lanes load 8 different metas, shfl-broadcast) -> 8 gathers in flight.
// Padded CSR -> no guards at all.
__global__ __launch_bounds__(256) void spmm26_bf(
    const u32x2* __restrict__ meta, const int* __restrict__ start,
    const uint_t* __restrict__ in, const uint_t* __restrict__ add,
    uint_t* __restrict__ out, int n) {
  int node = blockIdx.x * 32 + (threadIdx.x >> 3);
  int ln = threadIdx.x & 7;
  if (node >= n) return;
  int s = start[node], mp = start[node + 1] - s;
  uint_t foff = (uint_t)ln << 3;  // byte offset within 64B row
  const char* inb = (const char*)in;
  float a0 = 0.f, a1 = 0.f, a2 = 0.f, a3 = 0.f;
  for (int base = 0; base < mp; base += 8) {
    u32x2 mt = meta[s + base + ln];
    int rr = (int)mt.x;
    float ww = __uint_as_float(mt.y);
#pragma unroll
    for (int k = 0; k < 8; ++k) {
      uint_t r = (uint_t)__shfl(rr, k, 8);
      float wv = __shfl(ww, k, 8);
      u32x2 v = *reinterpret_cast<const u32x2*>(inb + ((r << 6) + foff));
      a0 += wv * lo16(v.x); a1 += wv * hi16(v.x);
      a2 += wv * lo16(v.y); a3 += wv * hi16(v.y);
    }
  }
  if (add) {
    u32x2 v = *reinterpret_cast<const u32x2*>(add + (size_t)node * 16 + 2 * ln);
    a0 += lo16(v.x); a1 += hi16(v.x);
    a2 += lo16(v.y); a3 += hi16(v.y);
  }
  u32x2 o;
  o.x = pack2(a0, a1);
  o.y = pack2(a2, a3);
  *reinterpret_cast<u32x2*>(out + (size_t)node * 16 + 2 * ln) = o;
}

// final Horner step: out_f32 (n x 26) += A*in
__global__ __launch_bounds__(256) void spmm26_addf(
    const u32x2* __restrict__ meta, const int* __restrict__ start,
    const uint_t* __restrict__ in, float* __restrict__ out, int n) {
  int node = blockIdx.x * 32 + (threadIdx.x >> 3);
  int ln = threadIdx.x & 7;
  if (node >= n) return;
  int s = start[node], mp = start[node + 1] - s;
  uint_t foff = (uint_t)ln << 3;
  const char* inb = (const char*)in;
  float a0 = 0.f, a1 = 0.f, a2 = 0.f, a3 = 0.f;
  for (int base = 0; base < mp; base += 8) {
    u32x2 mt = meta[s + base + ln];
    int rr = (int)mt.x;
    float ww = __uint_as_float(mt.y);
#pragma unroll
    for (int k = 0; k < 8; ++k) {
      uint_t r = (uint_t)__shfl(rr, k, 8);
      float wv = __shfl(ww, k, 8);
      u32x2 v = *reinterpret_cast<const u32x2*>(inb + ((r << 6) + foff));
      a0 += wv * lo16(v.x); a1 += wv * hi16(v.x);
      a2 += wv * lo16(v.y); a3 += wv * hi16(v.y);
    }
  }
  int c0 = 4 * ln;
  if (c0 + 0 < 26) out[(size_t)node * 26 + c0 + 0] += a0;
  if (c0 + 1 < 26) out[(size_t)node * 26 + c0 + 1] += a1;
  if (c0 + 2 < 26) out[(size_t)node * 26 + c0 + 2] += a2;
  if (c0 + 3 < 26) out[(size_t)node * 26 + c0 + 3] += a3;
}

// ---------------- fused MFMA GEMM: double-buffered LDS W, 1 barrier/group ----------------
// C(n x 128) = [A0|A1|A2|A3] (each n x KW bf16) @ Wswz (+bias)
// Per group g: [issue loads g+1] -> [compute sW[g&1]] -> [write sW[(g+1)&1]] -> barrier.
// Race-free with ONE barrier/group: a wave writing sW[(g+1)&1] can only coexist with
// laggards in compute(sW[g&1]) (different buffer); readers of sW[(g+1)&1] (group g-1's
// compute) all finished before the g-1 barrier. Compute never waits on its own group's
// LDS write; load latency (A and W) hides under the MFMA phase.
// EPI 0: ELU, write bf16 n x 128 to outb
// EPI 1: layer-3 slots: slot0 -> outf (n x 26 fp32, +bias); slots 1..3 -> outb (3 x n x 32 bf16)
template <int KW, int NSRC, int EPI, int GROUP>
__global__ __launch_bounds__(256) void mfma_gemm(
    const ushort_t* __restrict__ A0, const ushort_t* __restrict__ A1,
    const ushort_t* __restrict__ A2, const ushort_t* __restrict__ A3,
    const ushort_t* __restrict__ Wswz, const float* __restrict__ bias,
    ushort_t* __restrict__ outb, float* __restrict__ outf, int n) {
  constexpr int KSPS = KW / 32;
  constexpr int KSTEPS = NSRC * KSPS;
  constexpr int NGROUPS = KSTEPS / GROUP;
  __shared__ ushort_t sW[2][GROUP * 4096];
  const int tid = threadIdx.x;
  const int w = tid >> 6;
  const int l = tid & 63;
  const int row0 = blockIdx.x * 64 + w * 16;
  const int koff = 8 * (l >> 4);  // elements
  const int arow = row0 + (l & 15);
  const int arow_c = arow < n ? arow : (n - 1);

  f32x4 acc[8];
#pragma unroll
  for (int j = 0; j < 8; ++j) acc[j] = (f32x4){0.f, 0.f, 0.f, 0.f};

  const ushort_t* const srcs[4] = {A0, A1, A2, A3};

  auto aload = [&](int t) {
    const int s = t / KSPS;
    const int tt = t - s * KSPS;
    return ld_frag(srcs[s] + (size_t)arow_c * KW + tt * 32 + koff);
  };

  // parity register sets: even groups use afA/gwA, odd use afB/gwB
  bf16x8 afA[GROUP], afB[GROUP];
  u32x4 gwA[2 * GROUP], gwB[2 * GROUP];

  // prologue: load group 0 (A + W), write sW[0], barrier
#pragma unroll
  for (int c = 0; c < GROUP; ++c) {
    afA[c] = aload(c);
    const ushort_t* p = Wswz + (size_t)c * 4096 + tid * 8;
    gwA[2 * c] = *reinterpret_cast<const u32x4*>(p);
    gwA[2 * c + 1] = *reinterpret_cast<const u32x4*>(p + 2048);
  }
#pragma unroll
  for (int c = 0; c < GROUP; ++c) {
    *reinterpret_cast<u32x4*>(&sW[0][c * 4096 + tid * 8]) = gwA[2 * c];
    *reinterpret_cast<u32x4*>(&sW[0][c * 4096 + tid * 8 + 2048]) = gwA[2 * c + 1];
  }
  __syncthreads();

#pragma unroll
  for (int g = 0; g < NGROUPS; ++g) {
    const bool even = (g & 1) == 0;
    // issue next group's loads into the opposite register set
    if (g + 1 < NGROUPS) {
#pragma unroll
      for (int c = 0; c < GROUP; ++c) {
        const ushort_t* p = Wswz + (size_t)(g + 1) * GROUP * 4096 + (size_t)c * 4096 + tid * 8;
        if (even) {
          gwB[2 * c] = *reinterpret_cast<const u32x4*>(p);
          gwB[2 * c + 1] = *reinterpret_cast<const u32x4*>(p + 2048);
          afB[c] = aload((g + 1) * GROUP + c);
        } else {
          gwA[2 * c] = *reinterpret_cast<const u32x4*>(p);
          gwA[2 * c + 1] = *reinterpret_cast<const u32x4*>(p + 2048);
          afA[c] = aload((g + 1) * GROUP + c);
        }
      }
    }
    // compute current group from sW[g&1]
#pragma unroll
    for (int tg = 0; tg < GROUP; ++tg) {
      bf16x8 af = even ? afA[tg] : afB[tg];
      const ushort_t* wp = &sW[g & 1][tg * 4096 + l * 8];
#pragma unroll
      for (int j = 0; j < 8; ++j) {
        bf16x8 bfr = ld_frag(wp + j * 64 * 8);
        acc[j] = __builtin_amdgcn_mfma_f32_16x16x32_bf16(af, bfr, acc[j], 0, 0, 0);
      }
    }
    // write next group's W into the other LDS buffer (waitcnt overlapped with MFMAs above)
    if (g + 1 < NGROUPS) {
#pragma unroll
      for (int c = 0; c < GROUP; ++c) {
        u32x4 lo = even ? gwB[2 * c] : gwA[2 * c];
        u32x4 hi = even ? gwB[2 * c + 1] : gwA[2 * c + 1];
        *reinterpret_cast<u32x4*>(&sW[(g + 1) & 1][c * 4096 + tid * 8]) = lo;
        *reinterpret_cast<u32x4*>(&sW[(g + 1) & 1][c * 4096 + tid * 8 + 2048]) = hi;
      }
    }
    __syncthreads();
  }

  const int ccol = l & 15;
  const int crow0 = row0 + 4 * (l >> 4);
#pragma unroll
  for (int j = 0; j < 8; ++j) {
    if (EPI == 0) {
      int col = 16 * j + ccol;
      float bi = bias[col];
#pragma unroll
      for (int r = 0; r < 4; ++r) {
        int row = crow0 + r;
        if (row >= n) continue;
        float v = acc[j][r] + bi;
        v = v > 0.f ? v : (__expf(v) - 1.f);
        outb[(size_t)row * 128 + col] = f2b(v);
      }
    } else {
      int slot = j >> 1;
      int c = 16 * (j & 1) + ccol;
#pragma unroll
      for (int r = 0; r < 4; ++r) {
        int row = crow0 + r;
        if (row >= n) continue;
        float v = acc[j][r];
        if (slot == 0) {
          if (c < 26) outf[(size_t)row * 26 + c] = v + bias[c];
        } else {
          outb[((size_t)(slot - 1) * n + row) * 32 + c] = f2b(v);
        }
      }
    }
  }
}

// ---------------- launcher ----------------

extern "C" void kernel_launch(void* const* d_in, const int* in_sizes, int n_in,
                              void* d_out, int out_size, void* d_ws, size_t ws_size,
                              hipStream_t stream) {
  const float* x  = (const float*)d_in[0];
  const int*   ei = (const int*)d_in[1];
  const float* ew = (const float*)d_in[2];
  const float* W1 = (const float*)d_in[3];
  const float* b1 = (const float*)d_in[4];
  const float* W2 = (const float*)d_in[5];
  const float* b2 = (const float*)d_in[6];
  const float* W3 = (const float*)d_in[7];
  const float* b3 = (const float*)d_in[8];
  float* out = (float*)d_out;

  const int n = in_sizes[0] / NCLS;  // 100000
  const int E = in_sizes[2];         // 1600000
  const int nbk = (n + 255) >> 8;    // 391 buckets

  char* w = (char*)d_ws;
  auto alloc = [&](size_t bytes) {
    char* p = w;
    w += (bytes + 255) / 256 * 256;
    return p;
  };
  // width-128 bf16 feature buffers (64 dwords per node)
  uint_t* H0 = (uint_t*)alloc((size_t)n * 64 * 4);
  uint_t* P1 = (uint_t*)alloc((size_t)n * 64 * 4);
  uint_t* P2 = (uint_t*)alloc((size_t)n * 64 * 4);
  uint_t* P3 = (uint_t*)alloc((size_t)n * 64 * 4);
  uint_t* H1 = (uint_t*)alloc((size_t)n * 64 * 4);
  // width-32-padded bf16 buffers (16 dwords per node)
  uint_t* x32 = (uint_t*)alloc((size_t)n * 16 * 4);
  uint_t* q1  = (uint_t*)alloc((size_t)n * 16 * 4);
  uint_t* q2  = (uint_t*)alloc((size_t)n * 16 * 4);
  uint_t* q3  = (uint_t*)alloc((size_t)n * 16 * 4);
  uint_t* zb  = (uint_t*)alloc((size_t)n * 48 * 4);  // z1,z2,z3 each n x 32 bf16
  // swizzled weights
  ushort_t* Wz1 = (ushort_t*)alloc(4 * 4096 * 2);
  ushort_t* Wz2 = (ushort_t*)alloc(16 * 4096 * 2);
  ushort_t* Wz3 = (ushort_t*)alloc(4 * 4096 * 2);
  // graph CSR (padded)
  u64*   bkt  = (u64*)zb;  // alias: bkt (18.8MB @ BCAP=6016) dead before zb (19.2MB) is used
  u32x2* meta = (u32x2*)alloc(((size_t)E + 7 * (size_t)n + 64) * 8);
  int*   start = (int*)alloc((size_t)(n + 1) * 4);
  float* dinv  = (float*)alloc((size_t)n * 4);
  int*   gcur  = (int*)alloc(MAXBK * 4);
  int*   pbs   = (int*)alloc(MAXBK * 4);
  int*   pbase = (int*)alloc((MAXBK + 1) * 4);

  const int ab = (E + EPB - 1) / EPB;  // bucketing blocks (196)
  const int gconv = (n * 16 + 255) / 256;

  // independent small prep (x conversion + W swizzles) in one launch
  prep_misc<<<gconv + 64 + 256 + 64, 256, 0, stream>>>(x, x32, W1, Wz1, W2, Wz2, W3, Wz3,
                                                       n, gconv);

  hipMemsetAsync(gcur, 0, MAXBK * 4, stream);
  bucket_place<<<ab, 256, 0, stream>>>(ei, ew, gcur, bkt, E, nbk);
  bucket_stats<<<nbk, 256, 0, stream>>>(bkt, gcur, start, pbs, dinv, n);
  scan_pb<<<1, 512, 0, stream>>>(pbs, pbase, start, nbk, n);
  bucket_emit<<<nbk, 256, 0, stream>>>(bkt, gcur, pbase, start, dinv, meta, n);

  const int g128 = (n + 3) / 4;
  const int g26  = (n + 31) / 32;
  const int gg   = (n + 63) / 64;  // mfma_gemm grid (64 rows/block)

  // ---- Layer 1: q_k = A^k x (width 32-padded), H0 = ELU([x|q1|q2|q3] @ W1cat + b1) ----
  spmm26_bf<<<g26, 256, 0, stream>>>(meta, start, x32, nullptr, q1, n);
  spmm26_bf<<<g26, 256, 0, stream>>>(meta, start, q1, nullptr, q2, n);
  spmm26_bf<<<g26, 256, 0, stream>>>(meta, start, q2, nullptr, q3, n);
  mfma_gemm<32, 4, 0, 2><<<gg, 256, 0, stream>>>(
      (const ushort_t*)x32, (const ushort_t*)q1, (const ushort_t*)q2, (const ushort_t*)q3,
      Wz1, b1, (ushort_t*)H0, nullptr, n);

  // ---- Layer 2: P_k = A^k H0, H1 = ELU([H0|P1|P2|P3] @ W2cat + b2) ----
  spmm128_bf<<<g128, 256, 0, stream>>>(meta, start, H0, P1, n);
  spmm128_bf<<<g128, 256, 0, stream>>>(meta, start, P1, P2, n);
  spmm128_bf<<<g128, 256, 0, stream>>>(meta, start, P2, P3, n);
  mfma_gemm<128, 4, 0, 2><<<gg, 256, 0, stream>>>(
      (const ushort_t*)H0, (const ushort_t*)P1, (const ushort_t*)P2, (const ushort_t*)P3,
      Wz2, b2, (ushort_t*)H1, nullptr, n);

  // ---- Layer 3: Z = H1 @ [W3_0|W3_1|W3_2|W3_3]; Horner out = z0+b3 + A(z1 + A(z2 + A z3)) ----
  // NOTE: zb aliases bkt, which is dead after bucket_emit — safe.
  mfma_gemm<128, 1, 1, 2><<<gg, 256, 0, stream>>>(
      (const ushort_t*)H1, (const ushort_t*)H1, (const ushort_t*)H1, (const ushort_t*)H1,
      Wz3, b3, (ushort_t*)zb, out, n);

  uint_t* z1 = zb;
  uint_t* z2 = zb + (size_t)n * 16;
  uint_t* z3 = zb + (size_t)n * 32;
  spmm26_bf<<<g26, 256, 0, stream>>>(meta, start, z3, z2, q1, n);  // q1 = z2 + A z3
  spmm26_bf<<<g26, 256, 0, stream>>>(meta, start, q1, z1, q2, n);  // q2 = z1 + A q1
  spmm26_addf<<<g26, 256, 0, stream>>>(meta, start, q2, out, n);   // out += A q2
}